// Round 1
// baseline (270.830 us; speedup 1.0000x reference)
//
#include <hip/hip_runtime.h>
#include <cstdint>

#define BB    4096
#define TT    96
#define NC    85
#define BLANKC 84
#define DD    64
#define ALPHA 0.05f
#define BT    (BB * TT)      // 393216
#define NG    (BT / 4)       // 98304 groups of 4 (b,t) pairs
#define LSTR  65             // padded LDS stride per class row

// ---------------------------------------------------------------------------
// Kernel 1: per-(b,t) argmax over 85 classes. One wave per (b,t).
// Lane l holds preds[row, l] and (l<21) preds[row, l+64]; butterfly reduce
// (value, index) with first-index tie-break to match jnp.argmax.
// ---------------------------------------------------------------------------
__global__ __launch_bounds__(256) void k_argmax(const float* __restrict__ preds,
                                                unsigned char* __restrict__ pl) {
    int wave = blockIdx.x * 4 + (threadIdx.x >> 6);   // grid is exactly BT/4 blocks
    int lane = threadIdx.x & 63;
    const float* row = preds + (size_t)wave * NC;
    float v = row[lane];
    int   bi = lane;
    if (lane < NC - 64) {
        float v1 = row[lane + 64];
        if (v1 > v) { v = v1; bi = lane + 64; }
    }
#pragma unroll
    for (int off = 32; off; off >>= 1) {
        float ov = __shfl_xor(v, off);
        int   oi = __shfl_xor(bi, off);
        if (ov > v || (ov == v && oi < bi)) { v = ov; bi = oi; }
    }
    if (lane == 0) pl[wave] = (unsigned char)bi;
}

// ---------------------------------------------------------------------------
// Kernel 2: CTC collapse mask + per-class counts of masked positions.
// mask[b,t] = (pl != BLANK) && (t == T-1 || pl[t] != pl[t+1])
// ---------------------------------------------------------------------------
__global__ __launch_bounds__(256) void k_mask(const unsigned char* __restrict__ pl,
                                              const int* __restrict__ labels,
                                              unsigned char* __restrict__ maskb,
                                              int* __restrict__ counts) {
    __shared__ int h[NC];
    int tid = threadIdx.x;
    for (int i = tid; i < NC; i += 256) h[i] = 0;
    __syncthreads();
    int idx = blockIdx.x * 256 + tid;                 // grid is exactly BT/256
    int p = pl[idx];
    int t = idx % TT;
    int m = (p != BLANKC) && (t == TT - 1 || p != pl[idx + 1]);
    maskb[idx] = (unsigned char)m;
    atomicAdd(&h[labels[idx]], m);
    __syncthreads();
    for (int i = tid; i < NC; i += 256)
        if (h[i]) atomicAdd(&counts[i], h[i]);
}

// ---------------------------------------------------------------------------
// Kernel 3: main pass. Wave handles 4 (b,t) pairs/iter (lane&15 -> 4 dims as
// float4; lane>>4 -> which pair), 2-way unrolled. Loss partial in registers;
// delta accumulated into per-block LDS upd[85][65] (stride 65 spreads the 4
// pair-groups across disjoint bank sets). Per-block partials -> ws.
// ---------------------------------------------------------------------------
__global__ __launch_bounds__(256) void k_main(const float4* __restrict__ f4,
                                              const int* __restrict__ labels,
                                              const unsigned char* __restrict__ maskb,
                                              const int* __restrict__ counts,
                                              const float4* __restrict__ c4,
                                              float* __restrict__ updp,
                                              float* __restrict__ lossp, int nb) {
    __shared__ float lupd[NC * LSTR];
    __shared__ float lred[4];
    int tid = threadIdx.x;
    for (int i = tid; i < NC * LSTR; i += 256) lupd[i] = 0.f;
    __syncthreads();

    int lane = tid & 63;
    int wv   = tid >> 6;
    int gw   = blockIdx.x * 4 + wv;
    int nw   = nb * 4;
    int sub  = lane >> 4;
    int l15  = lane & 15;
    float lsum = 0.f;

    for (int g = gw; g < NG; g += 2 * nw) {
        int g2 = g + nw;
        bool has2 = (g2 < NG);
        // issue both loads up front
        float4 fa = f4[(size_t)g * 64 + lane];
        int   pa = g * 4 + sub;
        int   la = labels[pa];
        float ma = (float)maskb[pa];
        float4 fb = make_float4(0.f, 0.f, 0.f, 0.f);
        int lb = 0; float mb = 0.f;
        if (has2) {
            fb = f4[(size_t)g2 * 64 + lane];
            int pb = g2 * 4 + sub;
            lb = labels[pb];
            mb = (float)maskb[pb];
        }
        {
            float4 c = c4[la * 16 + l15];
            float sc = ma * (ALPHA / (1.f + (float)counts[la]));
            float d0 = c.x - fa.x, d1 = c.y - fa.y, d2 = c.z - fa.z, d3 = c.w - fa.w;
            lsum += ma * (d0 * d0 + d1 * d1 + d2 * d2 + d3 * d3);
            float* bp = &lupd[la * LSTR + l15 * 4];
            atomicAdd(bp + 0, sc * d0);
            atomicAdd(bp + 1, sc * d1);
            atomicAdd(bp + 2, sc * d2);
            atomicAdd(bp + 3, sc * d3);
        }
        if (has2) {
            float4 c = c4[lb * 16 + l15];
            float sc = mb * (ALPHA / (1.f + (float)counts[lb]));
            float d0 = c.x - fb.x, d1 = c.y - fb.y, d2 = c.z - fb.z, d3 = c.w - fb.w;
            lsum += mb * (d0 * d0 + d1 * d1 + d2 * d2 + d3 * d3);
            float* bp = &lupd[lb * LSTR + l15 * 4];
            atomicAdd(bp + 0, sc * d0);
            atomicAdd(bp + 1, sc * d1);
            atomicAdd(bp + 2, sc * d2);
            atomicAdd(bp + 3, sc * d3);
        }
    }
    __syncthreads();

    // flush upd partial (de-pad 65 -> 64 stride)
    float* myp = updp + (size_t)blockIdx.x * (NC * DD);
    for (int i = tid; i < NC * DD; i += 256)
        myp[i] = lupd[(i >> 6) * LSTR + (i & 63)];

    // loss partial: wave butterfly -> LDS -> thread 0
#pragma unroll
    for (int off = 32; off; off >>= 1) lsum += __shfl_xor(lsum, off);
    if (lane == 0) lred[wv] = lsum;
    __syncthreads();
    if (tid == 0) lossp[blockIdx.x] = lred[0] + lred[1] + lred[2] + lred[3];
}

// ---------------------------------------------------------------------------
// Kernel 4: reduce nb partials. Blocks 0..84 each produce 64 center dims
// (4 chunk-waves split the nb sum, coalesced across j); block 85 reduces loss.
// ---------------------------------------------------------------------------
__global__ __launch_bounds__(256) void k_reduce(const float* __restrict__ updp,
                                                const float* __restrict__ lossp,
                                                const float* __restrict__ centers,
                                                float* __restrict__ out, int nb) {
    __shared__ float sred[4 * 64];
    int tid = threadIdx.x;
    if (blockIdx.x < NC) {
        int lane  = tid & 63;
        int chunk = tid >> 6;
        int j = blockIdx.x * 64 + lane;
        int per = (nb + 3) / 4;
        int b0 = chunk * per;
        int b1 = min(nb, b0 + per);
        float s = 0.f;
        for (int b = b0; b < b1; ++b) s += updp[(size_t)b * (NC * DD) + j];
        sred[chunk * 64 + lane] = s;
        __syncthreads();
        if (chunk == 0) {
            float tot = sred[lane] + sred[64 + lane] + sred[128 + lane] + sred[192 + lane];
            out[1 + j] = centers[j] - tot;
        }
    } else {
        float s = 0.f;
        for (int i = tid; i < nb; i += 256) s += lossp[i];
#pragma unroll
        for (int off = 32; off; off >>= 1) s += __shfl_xor(s, off);
        int lane = tid & 63, wv = tid >> 6;
        if (lane == 0) sred[wv] = s;
        __syncthreads();
        if (tid == 0) out[0] = 0.5f * (sred[0] + sred[1] + sred[2] + sred[3]);
    }
}

// ---------------------------------------------------------------------------
extern "C" void kernel_launch(void* const* d_in, const int* in_sizes, int n_in,
                              void* d_out, int out_size, void* d_ws, size_t ws_size,
                              hipStream_t stream) {
    const float* preds    = (const float*)d_in[0];
    const float* features = (const float*)d_in[1];
    const int*   labels   = (const int*)d_in[2];
    const float* centers  = (const float*)d_in[3];
    float* out = (float*)d_out;

    char* ws = (char*)d_ws;
    unsigned char* pl    = (unsigned char*)ws;                 // BT bytes
    unsigned char* maskb = pl + BT;                            // BT bytes
    int* counts = (int*)(ws + 2 * (size_t)BT);                 // 85 ints
    size_t off = 2 * (size_t)BT + 512;                         // 786944, 16B-aligned

    int nb = 512;                                              // main-pass blocks
    while (nb > 4 && off + (size_t)nb * 4 + (size_t)nb * NC * DD * 4 > ws_size)
        nb >>= 1;
    float* lossp = (float*)(ws + off);
    float* updp  = (float*)(ws + off + (size_t)nb * 4);

    hipMemsetAsync(counts, 0, NC * sizeof(int), stream);
    k_argmax<<<BT / 4, 256, 0, stream>>>(preds, pl);
    k_mask<<<BT / 256, 256, 0, stream>>>(pl, labels, maskb, counts);
    k_main<<<nb, 256, 0, stream>>>((const float4*)features, labels, maskb, counts,
                                   (const float4*)centers, updp, lossp, nb);
    k_reduce<<<NC + 1, 256, 0, stream>>>(updp, lossp, centers, out, nb);
}

// Round 2
// 218.692 us; speedup vs baseline: 1.2384x; 1.2384x over previous
//
#include <hip/hip_runtime.h>
#include <cstdint>

#define BB     4096
#define TT     96
#define NC     85
#define BLANKC 84
#define DD     64
#define ALPHA  0.05f
#define BT     (BB * TT)     // 393216
#define NG     (BT / 4)      // 98304 groups of 4 (b,t) pairs
#define LSTR   65            // padded LDS stride per class row
#define ROWS_PER_BLK 96      // argmax rows per block

// ---------------------------------------------------------------------------
// Kernel 1: argmax over 85 classes. 4096 blocks x 256 thr; each block stages
// 96 rows (96*85 floats = 32.6 KB) to LDS via coalesced float4, then threads
// 0..95 each serially scan one row (stride-85 LDS reads: 85 odd -> 2-way max).
// ---------------------------------------------------------------------------
__global__ __launch_bounds__(256) void k_argmax(const float4* __restrict__ p4,
                                                unsigned char* __restrict__ pl) {
    __shared__ float rows[ROWS_PER_BLK * NC];    // 8160 floats
    int tid = threadIdx.x;
    const float4* src = p4 + (size_t)blockIdx.x * (ROWS_PER_BLK * NC / 4);
    float* rf4 = rows;
    for (int i = tid; i < ROWS_PER_BLK * NC / 4; i += 256) {
        float4 v = src[i];
        rf4[i * 4 + 0] = v.x; rf4[i * 4 + 1] = v.y;
        rf4[i * 4 + 2] = v.z; rf4[i * 4 + 3] = v.w;
    }
    __syncthreads();
    if (tid < ROWS_PER_BLK) {
        const float* r = rows + tid * NC;
        float best = r[0];
        int bi = 0;
#pragma unroll 4
        for (int c = 1; c < NC; ++c) {
            float v = r[c];
            if (v > best) { best = v; bi = c; }
        }
        pl[blockIdx.x * ROWS_PER_BLK + tid] = (unsigned char)bi;
    }
}

// ---------------------------------------------------------------------------
// Kernel 2: CTC collapse mask + per-class counts of masked positions.
// ---------------------------------------------------------------------------
__global__ __launch_bounds__(256) void k_mask(const unsigned char* __restrict__ pl,
                                              const int* __restrict__ labels,
                                              unsigned char* __restrict__ maskb,
                                              int* __restrict__ counts) {
    __shared__ int h[NC];
    int tid = threadIdx.x;
    for (int i = tid; i < NC; i += 256) h[i] = 0;
    __syncthreads();
    int idx = blockIdx.x * 256 + tid;
    int p = pl[idx];
    int t = idx % TT;
    int m = (p != BLANKC) && (t == TT - 1 || p != pl[idx + 1]);
    maskb[idx] = (unsigned char)m;
    atomicAdd(&h[labels[idx]], m);
    __syncthreads();
    for (int i = tid; i < NC; i += 256)
        if (h[i]) atomicAdd(&counts[i], h[i]);
}

// ---------------------------------------------------------------------------
// Kernel 3: masked feature segment-sum. F[j][d] = sum of masked features with
// label j (per-block LDS partial), plus Sfeat partial = sum of masked |f|^2.
// No label-dependent loads: f4/labels/maskb all independent, 4-way unrolled.
// nb blocks x 512 threads (8 waves). Wave handles 4 pairs (lane>>4 = pair,
// lane&15 -> 4 dims as float4).
// ---------------------------------------------------------------------------
__global__ __launch_bounds__(512) void k_main(const float4* __restrict__ f4,
                                              const int* __restrict__ labels,
                                              const unsigned char* __restrict__ maskb,
                                              float* __restrict__ updp,
                                              float* __restrict__ lossp, int nb) {
    __shared__ float lupd[NC * LSTR];
    __shared__ float lred[8];
    int tid = threadIdx.x;
    for (int i = tid; i < NC * LSTR; i += 512) lupd[i] = 0.f;
    __syncthreads();

    int lane = tid & 63;
    int wv   = tid >> 6;
    int gw   = blockIdx.x * 8 + wv;
    int nw   = nb * 8;                 // total waves
    int sub  = lane >> 4;
    int l15  = lane & 15;
    float lsum = 0.f;

    // NG = 98304 = 2^15*3; nb power-of-2 <= 1024 -> exact division, no tails.
    int iters = NG / (4 * nw);
    int g = gw;
    for (int it = 0; it < iters; ++it, g += 4 * nw) {
        float4 fv[4]; int la[4]; float mm[4];
#pragma unroll
        for (int u = 0; u < 4; ++u) {
            int gg = g + u * nw;
            fv[u] = f4[(size_t)gg * 64 + lane];
            int pa = gg * 4 + sub;
            la[u] = labels[pa];
            mm[u] = (float)maskb[pa];
        }
#pragma unroll
        for (int u = 0; u < 4; ++u) {
            float m = mm[u];
            float4 f = fv[u];
            lsum = fmaf(m * f.x, f.x, lsum);
            lsum = fmaf(m * f.y, f.y, lsum);
            lsum = fmaf(m * f.z, f.z, lsum);
            lsum = fmaf(m * f.w, f.w, lsum);
            int base = la[u] * LSTR + l15 * 4;
            atomicAdd(&lupd[base + 0], m * f.x);
            atomicAdd(&lupd[base + 1], m * f.y);
            atomicAdd(&lupd[base + 2], m * f.z);
            atomicAdd(&lupd[base + 3], m * f.w);
        }
    }
    __syncthreads();

    // flush F partial (de-pad 65 -> 64 stride), coalesced
    float* myp = updp + (size_t)blockIdx.x * (NC * DD);
    for (int i = tid; i < NC * DD; i += 512)
        myp[i] = lupd[(i >> 6) * LSTR + (i & 63)];

    // Sfeat partial: wave butterfly -> LDS -> thread 0
#pragma unroll
    for (int off = 32; off; off >>= 1) lsum += __shfl_xor(lsum, off);
    if (lane == 0) lred[wv] = lsum;
    __syncthreads();
    if (tid == 0) {
        float s = 0.f;
#pragma unroll
        for (int w = 0; w < 8; ++w) s += lred[w];
        lossp[blockIdx.x] = s;
    }
}

// ---------------------------------------------------------------------------
// Kernel 4: blocks 0..84: reduce F_j over nb partials, compute new centers and
// per-class loss piece cnt_j*|c_j|^2 - 2 c_j . F_j -> lossc[j].
// Block 85: Sfeat = sum lossp -> lossc[85].
// ---------------------------------------------------------------------------
__global__ __launch_bounds__(256) void k_reduce(const float* __restrict__ updp,
                                                const float* __restrict__ lossp,
                                                const float* __restrict__ centers,
                                                const int* __restrict__ counts,
                                                float* __restrict__ out,
                                                float* __restrict__ lossc, int nb) {
    __shared__ float sred[4 * 64];
    int tid = threadIdx.x;
    int j = blockIdx.x;
    if (j < NC) {
        int lane  = tid & 63;
        int chunk = tid >> 6;
        int per = nb >> 2;
        int b0 = chunk * per;
        float s = 0.f;
        for (int b = b0; b < b0 + per; ++b)
            s += updp[(size_t)b * (NC * DD) + j * DD + lane];
        sred[chunk * 64 + lane] = s;
        __syncthreads();
        if (chunk == 0) {
            float F = sred[lane] + sred[64 + lane] + sred[128 + lane] + sred[192 + lane];
            float c = centers[j * DD + lane];
            float cnt = (float)counts[j];
            float scale = ALPHA / (1.f + cnt);
            out[1 + j * DD + lane] = c - scale * (cnt * c - F);
            float lp = cnt * c * c - 2.f * c * F;   // per-dim loss piece
#pragma unroll
            for (int off = 32; off; off >>= 1) lp += __shfl_xor(lp, off);
            if (lane == 0) lossc[j] = lp;
        }
    } else {
        float s = 0.f;
        for (int i = tid; i < nb; i += 256) s += lossp[i];
#pragma unroll
        for (int off = 32; off; off >>= 1) s += __shfl_xor(s, off);
        int lane = tid & 63, wv = tid >> 6;
        if (lane == 0) sred[wv] = s;
        __syncthreads();
        if (tid == 0) lossc[NC] = sred[0] + sred[1] + sred[2] + sred[3];
    }
}

// ---------------------------------------------------------------------------
// Kernel 5: out[0] = 0.5 * sum(lossc[0..85])
// ---------------------------------------------------------------------------
__global__ __launch_bounds__(128) void k_final(const float* __restrict__ lossc,
                                               float* __restrict__ out) {
    __shared__ float sr[2];
    int tid = threadIdx.x;
    float s = (tid <= NC) ? lossc[tid] : 0.f;
#pragma unroll
    for (int off = 32; off; off >>= 1) s += __shfl_xor(s, off);
    int lane = tid & 63, wv = tid >> 6;
    if (lane == 0) sr[wv] = s;
    __syncthreads();
    if (tid == 0) out[0] = 0.5f * (sr[0] + sr[1]);
}

// ---------------------------------------------------------------------------
extern "C" void kernel_launch(void* const* d_in, const int* in_sizes, int n_in,
                              void* d_out, int out_size, void* d_ws, size_t ws_size,
                              hipStream_t stream) {
    const float* preds    = (const float*)d_in[0];
    const float* features = (const float*)d_in[1];
    const int*   labels   = (const int*)d_in[2];
    const float* centers  = (const float*)d_in[3];
    float* out = (float*)d_out;

    char* ws = (char*)d_ws;
    unsigned char* pl    = (unsigned char*)ws;                 // BT bytes
    unsigned char* maskb = pl + BT;                            // BT bytes
    int* counts = (int*)(ws + 2 * (size_t)BT);                 // 85 ints (pad 512)
    size_t off0 = 2 * (size_t)BT + 512;                        // 786944

    int nb = 256;                                              // main-pass blocks
    while (nb > 4 && off0 + (size_t)nb * 4 + 512 + 512 +
                     (size_t)nb * NC * DD * 4 > ws_size)
        nb >>= 1;
    float* lossp = (float*)(ws + off0);                        // nb floats
    float* lossc = (float*)(ws + off0 + (size_t)nb * 4);       // 86 floats (pad 512)
    float* updp  = (float*)(ws + off0 + (size_t)nb * 4 + 1024);

    hipMemsetAsync(counts, 0, NC * sizeof(int), stream);
    k_argmax<<<BT / ROWS_PER_BLK, 256, 0, stream>>>((const float4*)preds, pl);
    k_mask<<<BT / 256, 256, 0, stream>>>(pl, labels, maskb, counts);
    k_main<<<nb, 512, 0, stream>>>((const float4*)features, labels, maskb,
                                   updp, lossp, nb);
    k_reduce<<<NC + 1, 256, 0, stream>>>(updp, lossp, centers, counts,
                                         out, lossc, nb);
    k_final<<<1, 128, 0, stream>>>(lossc, out);
}

// Round 3
// 141.484 us; speedup vs baseline: 1.9142x; 1.5457x over previous
//
#include <hip/hip_runtime.h>
#include <cstdint>

#define BB     4096
#define TT     96
#define NC     85
#define BLANKC 84
#define DD     64
#define ALPHA  0.05f
#define BT     (BB * TT)      // 393216
#define SLICE_F (NC * 17)     // 1445 floats per wave-private slice (pad 16->17)

// ---------------------------------------------------------------------------
// Kernel 1: argmax. Each thread scans 4 consecutive rows (4*85 floats =
// 1360 B, 16B-aligned) via 85 float4 loads, fully unrolled so row/col are
// compile-time. Stride-1360 wave pattern stays L1-resident (4 KB window).
// ---------------------------------------------------------------------------
__global__ __launch_bounds__(256) void k_argmax(const float4* __restrict__ p4,
                                                uchar4* __restrict__ pl4) {
    int g = blockIdx.x * 256 + threadIdx.x;        // 0 .. BT/4-1
    const float4* base = p4 + (size_t)g * 85;
    float best[4]; int bi[4];
#pragma unroll
    for (int r = 0; r < 4; ++r) { best[r] = -3.4e38f; bi[r] = 0; }
#pragma unroll
    for (int i = 0; i < 85; ++i) {
        float4 v = base[i];
        float vv[4] = {v.x, v.y, v.z, v.w};
#pragma unroll
        for (int j = 0; j < 4; ++j) {
            int ee = i * 4 + j;
            int r = ee / 85, c = ee - r * 85;      // compile-time
            if (vv[j] > best[r]) { best[r] = vv[j]; bi[r] = c; }
        }
    }
    pl4[g] = make_uchar4((unsigned char)bi[0], (unsigned char)bi[1],
                         (unsigned char)bi[2], (unsigned char)bi[3]);
}

// ---------------------------------------------------------------------------
// Kernel 2: CTC mask + per-class counts + packed label/mask word.
// labm[idx] = label | (mask << 31)
// ---------------------------------------------------------------------------
__global__ __launch_bounds__(256) void k_mask(const unsigned char* __restrict__ pl,
                                              const int* __restrict__ labels,
                                              unsigned* __restrict__ labm,
                                              int* __restrict__ counts) {
    __shared__ int h[NC];
    int tid = threadIdx.x;
    if (tid < NC) h[tid] = 0;
    __syncthreads();
    int idx = blockIdx.x * 256 + tid;
    int p = pl[idx];
    int t = idx % TT;
    unsigned m = (p != BLANKC) && (t == TT - 1 || p != pl[idx + 1]);
    labm[idx] = (unsigned)labels[idx] | (m << 31);
    atomicAdd(&h[labels[idx]], (int)m);
    __syncthreads();
    if (tid < NC && h[tid]) atomicAdd(&counts[tid], h[tid]);
}

// ---------------------------------------------------------------------------
// Kernel 3: masked feature segment-sum, NO LDS atomics on the hot path.
// 8 waves/block; wave w owns dim-quad dq=w&3 with a PRIVATE slice [85][17].
// Per step a wave handles 4 positions x 16 dims (lane>>4 = position,
// lane&15 = dim): plain ds_read+fma+ds_write — addresses provably distinct
// when the 4 labels are distinct (93%); shuffle-detected dup steps fall back
// to LDS atomicAdd. 24 waves/CU (46.3 KB LDS -> 3 blocks/CU).
// ---------------------------------------------------------------------------
__global__ __launch_bounds__(512) void k_main(const float* __restrict__ feat,
                                              const unsigned* __restrict__ labm,
                                              float* __restrict__ updp,
                                              float* __restrict__ lossp, int nb) {
    __shared__ float sl[8 * SLICE_F];              // 46240 B
    __shared__ float lred[8];
    int tid = threadIdx.x;
    for (int i = tid; i < 8 * SLICE_F; i += 512) sl[i] = 0.f;
    __syncthreads();

    int lane = tid & 63;
    int w    = tid >> 6;
    int dq   = w & 3;
    int wg   = w >> 2;
    int sub  = lane >> 4;
    int l16  = lane & 15;
    float* slice = sl + w * SLICE_F;

    int ppc    = BT / (nb * 2);                    // positions per chunk
    int p0     = (blockIdx.x * 2 + wg) * ppc;
    int nsteps = ppc / 4;

    float lsum = 0.f;
    unsigned lm = labm[p0 + sub];
    float    f  = feat[(size_t)(p0 + sub) * DD + dq * 16 + l16];

    for (int s = 0; s < nsteps; ++s) {
        unsigned lm_c = lm; float f_c = f;
        if (s + 1 < nsteps) {
            int pn = p0 + (s + 1) * 4 + sub;
            lm = labm[pn];
            f  = feat[(size_t)pn * DD + dq * 16 + l16];
        }
        float m = (float)(lm_c >> 31);
        int  la = (int)(lm_c & 0x7fffffffu);
        float c = m * f_c;
        lsum = fmaf(c, f_c, lsum);
        int a = la * 17 + l16;
        int l0 = __shfl(la, 0), l1 = __shfl(la, 16),
            l2 = __shfl(la, 32), l3 = __shfl(la, 48);
        bool dup = (l0 == l1) | (l0 == l2) | (l0 == l3) |
                   (l1 == l2) | (l1 == l3) | (l2 == l3);
        if (!dup) slice[a] += c;                   // distinct rows: race-free
        else      atomicAdd(&slice[a], c);         // rare (~7%) fallback
    }
    __syncthreads();

    // flush: block partial F[85][64] = slice[dq] + slice[dq+4]
    float* myp = updp + (size_t)blockIdx.x * (NC * DD);
    for (int i = tid; i < NC * DD; i += 512) {
        int r = i >> 6, d = i & 63;
        int q = d >> 4, d16 = d & 15;
        myp[i] = sl[q * SLICE_F + r * 17 + d16] +
                 sl[(q + 4) * SLICE_F + r * 17 + d16];
    }
#pragma unroll
    for (int off = 32; off; off >>= 1) lsum += __shfl_xor(lsum, off);
    if (lane == 0) lred[w] = lsum;
    __syncthreads();
    if (tid == 0) {
        float s = 0.f;
#pragma unroll
        for (int ww = 0; ww < 8; ++ww) s += lred[ww];
        lossp[blockIdx.x] = s;
    }
}

// ---------------------------------------------------------------------------
// Kernel 4: grid NC*4+1. Block (j,q) reduces F over nb partials for 16 dims,
// writes new centers + loss piece partial. Last block reduces Sfeat.
// ---------------------------------------------------------------------------
__global__ __launch_bounds__(256) void k_reduce(const float* __restrict__ updp,
                                                const float* __restrict__ lossp,
                                                const float* __restrict__ centers,
                                                const int* __restrict__ counts,
                                                float* __restrict__ out,
                                                float* __restrict__ lossc, int nb) {
    __shared__ float sred[256];
    __shared__ float sr[4];
    int tid = threadIdx.x;
    int bid = blockIdx.x;
    if (bid < NC * 4) {
        int j = bid >> 2, q = bid & 3;
        int i = tid & 15;
        int c16 = tid >> 4;
        int per = nb >> 4;
        int col = j * DD + q * 16 + i;
        float s = 0.f;
        for (int b = c16 * per; b < (c16 + 1) * per; ++b)
            s += updp[(size_t)b * (NC * DD) + col];
        sred[tid] = s;
        __syncthreads();
        if (tid < 16) {
            float F = 0.f;
#pragma unroll
            for (int cc = 0; cc < 16; ++cc) F += sred[cc * 16 + i];
            float c   = centers[col];
            float cnt = (float)counts[j];
            float scale = ALPHA / (1.f + cnt);
            out[1 + col] = c - scale * (cnt * c - F);
            float lp = cnt * c * c - 2.f * c * F;
#pragma unroll
            for (int off = 8; off; off >>= 1) lp += __shfl_xor(lp, off);
            if (i == 0) lossc[bid] = lp;
        }
    } else {
        float s = 0.f;
        for (int t = tid; t < nb; t += 256) s += lossp[t];
#pragma unroll
        for (int off = 32; off; off >>= 1) s += __shfl_xor(s, off);
        int lane = tid & 63, wv = tid >> 6;
        if (lane == 0) sr[wv] = s;
        __syncthreads();
        if (tid == 0) lossc[NC * 4] = sr[0] + sr[1] + sr[2] + sr[3];
    }
}

// ---------------------------------------------------------------------------
// Kernel 5: out[0] = 0.5 * sum(lossc[0 .. NC*4])
// ---------------------------------------------------------------------------
__global__ __launch_bounds__(512) void k_final(const float* __restrict__ lossc,
                                               float* __restrict__ out) {
    __shared__ float sr[8];
    int tid = threadIdx.x;
    float s = (tid < NC * 4 + 1) ? lossc[tid] : 0.f;
#pragma unroll
    for (int off = 32; off; off >>= 1) s += __shfl_xor(s, off);
    int lane = tid & 63, wv = tid >> 6;
    if (lane == 0) sr[wv] = s;
    __syncthreads();
    if (tid == 0) {
        float t = 0.f;
#pragma unroll
        for (int w2 = 0; w2 < 8; ++w2) t += sr[w2];
        out[0] = 0.5f * t;
    }
}

// ---------------------------------------------------------------------------
extern "C" void kernel_launch(void* const* d_in, const int* in_sizes, int n_in,
                              void* d_out, int out_size, void* d_ws, size_t ws_size,
                              hipStream_t stream) {
    const float* preds    = (const float*)d_in[0];
    const float* features = (const float*)d_in[1];
    const int*   labels   = (const int*)d_in[2];
    const float* centers  = (const float*)d_in[3];
    float* out = (float*)d_out;

    char* ws = (char*)d_ws;
    unsigned char* pl  = (unsigned char*)ws;                    // BT bytes
    unsigned* labm     = (unsigned*)(ws + BT);                  // BT words
    int* counts        = (int*)(ws + 5 * (size_t)BT);           // 85 ints
    size_t off0 = 5 * (size_t)BT + 512;

    int nb = 768;                                               // 3 blocks/CU
    while (nb > 16 && off0 + (size_t)nb * 4 + 1536 +
                      (size_t)nb * NC * DD * 4 > ws_size)
        nb >>= 1;
    float* lossp = (float*)(ws + off0);                         // nb floats
    float* lossc = (float*)(ws + off0 + (size_t)nb * 4);        // 341 floats
    float* updp  = (float*)(ws + off0 + (size_t)nb * 4 + 1536);

    hipMemsetAsync(counts, 0, NC * sizeof(int), stream);
    k_argmax<<<BT / 4 / 256, 256, 0, stream>>>((const float4*)preds, (uchar4*)pl);
    k_mask<<<BT / 256, 256, 0, stream>>>(pl, labels, labm, counts);
    k_main<<<nb, 512, 0, stream>>>(features, labm, updp, lossp, nb);
    k_reduce<<<NC * 4 + 1, 256, 0, stream>>>(updp, lossp, centers, counts,
                                             out, lossc, nb);
    k_final<<<1, 512, 0, stream>>>(lossc, out);
}

// Round 4
// 135.177 us; speedup vs baseline: 2.0035x; 1.0467x over previous
//
#include <hip/hip_runtime.h>
#include <cstdint>

#define BB     4096
#define TT     96
#define NC     85
#define BLANKC 84
#define DD     64
#define ALPHA  0.05f
#define BT     (BB * TT)      // 393216
#define SLICE_F (NC * 17)     // 1445 floats per wave-private slice (pad 16->17)

// ---------------------------------------------------------------------------
// Kernel 1: argmax over 85 classes, 4-row groups (85 aligned float4s) split
// across 4 waves (wave-uniform q -> compile-time float4 range, no divergence).
// Each thread batch-loads its 21-22 float4s straight-line (deep MLP), scans
// in registers, then a padded-LDS combine merges the 4 column-range partials
// with lower-column tie-break. 1536 blocks, ~16 waves/CU.
// ---------------------------------------------------------------------------
template<int I0, int I1>
__device__ inline void scan4(const float4* __restrict__ base,
                             float best[4], int bi[4]) {
    float4 f[I1 - I0];
#pragma unroll
    for (int k = 0; k < I1 - I0; ++k) f[k] = base[I0 + k];
#pragma unroll
    for (int k = 0; k < I1 - I0; ++k) {
        float vv[4] = {f[k].x, f[k].y, f[k].z, f[k].w};
#pragma unroll
        for (int j = 0; j < 4; ++j) {
            int e = (I0 + k) * 4 + j;
            int r = e / NC, c = e - r * NC;        // compile-time
            if (vv[j] > best[r]) { best[r] = vv[j]; bi[r] = c; }
        }
    }
}

__global__ __launch_bounds__(256) void k_argmax(const float4* __restrict__ p4,
                                                unsigned char* __restrict__ pl) {
    __shared__ float sv[4 * 64 * 5];               // [q][group][row] pad 4->5
    __shared__ int   sc[4 * 64 * 5];
    int tid  = threadIdx.x;
    int w    = tid >> 6;                           // q = wave index, uniform
    int lane = tid & 63;
    int grp  = blockIdx.x * 64 + lane;             // 4-row group id
    const float4* base = p4 + (size_t)grp * NC;

    float best[4]; int bi[4];
#pragma unroll
    for (int r = 0; r < 4; ++r) { best[r] = -3.4e38f; bi[r] = 127; }
    switch (w) {
        case 0: scan4< 0, 22>(base, best, bi); break;
        case 1: scan4<22, 43>(base, best, bi); break;
        case 2: scan4<43, 64>(base, best, bi); break;
        default: scan4<64, 85>(base, best, bi); break;
    }
#pragma unroll
    for (int r = 0; r < 4; ++r) {
        sv[(w * 64 + lane) * 5 + r] = best[r];
        sc[(w * 64 + lane) * 5 + r] = bi[r];
    }
    __syncthreads();

    // thread tid finalizes row (g = tid>>2, r = tid&3)
    int g = tid >> 2, r = tid & 3;
    float bv = -3.4e38f; int bc = 127;
#pragma unroll
    for (int q = 0; q < 4; ++q) {
        float v = sv[(q * 64 + g) * 5 + r];
        int   c = sc[(q * 64 + g) * 5 + r];
        if (v > bv || (v == bv && c < bc)) { bv = v; bc = c; }
    }
    pl[blockIdx.x * 256 + tid] = (unsigned char)bc;
}

// ---------------------------------------------------------------------------
// Kernel 2: CTC mask + per-class counts + packed label/mask word.
// labm[idx] = label | (mask << 31)
// ---------------------------------------------------------------------------
__global__ __launch_bounds__(256) void k_mask(const unsigned char* __restrict__ pl,
                                              const int* __restrict__ labels,
                                              unsigned* __restrict__ labm,
                                              int* __restrict__ counts) {
    __shared__ int h[NC];
    int tid = threadIdx.x;
    if (tid < NC) h[tid] = 0;
    __syncthreads();
    int idx = blockIdx.x * 256 + tid;
    int p = pl[idx];
    int t = idx % TT;
    unsigned m = (p != BLANKC) && (t == TT - 1 || p != pl[idx + 1]);
    labm[idx] = (unsigned)labels[idx] | (m << 31);
    atomicAdd(&h[labels[idx]], (int)m);
    __syncthreads();
    if (tid < NC && h[tid]) atomicAdd(&counts[tid], h[tid]);
}

// ---------------------------------------------------------------------------
// Kernel 3: masked feature segment-sum, NO LDS atomics on the hot path.
// 8 waves/block; wave w owns dim-quad dq=w&3 with a PRIVATE slice [85][17].
// Per step a wave handles 4 positions x 16 dims; plain ds_read+fma+ds_write
// when the 4 labels are distinct (93%); atomic fallback otherwise.
// ---------------------------------------------------------------------------
__global__ __launch_bounds__(512) void k_main(const float* __restrict__ feat,
                                              const unsigned* __restrict__ labm,
                                              float* __restrict__ updp,
                                              float* __restrict__ lossp, int nb) {
    __shared__ float sl[8 * SLICE_F];              // 46240 B
    __shared__ float lred[8];
    int tid = threadIdx.x;
    for (int i = tid; i < 8 * SLICE_F; i += 512) sl[i] = 0.f;
    __syncthreads();

    int lane = tid & 63;
    int w    = tid >> 6;
    int dq   = w & 3;
    int wg   = w >> 2;
    int sub  = lane >> 4;
    int l16  = lane & 15;
    float* slice = sl + w * SLICE_F;

    int ppc    = BT / (nb * 2);
    int p0     = (blockIdx.x * 2 + wg) * ppc;
    int nsteps = ppc / 4;

    float lsum = 0.f;
    unsigned lm = labm[p0 + sub];
    float    f  = feat[(size_t)(p0 + sub) * DD + dq * 16 + l16];

    for (int s = 0; s < nsteps; ++s) {
        unsigned lm_c = lm; float f_c = f;
        if (s + 1 < nsteps) {
            int pn = p0 + (s + 1) * 4 + sub;
            lm = labm[pn];
            f  = feat[(size_t)pn * DD + dq * 16 + l16];
        }
        float m = (float)(lm_c >> 31);
        int  la = (int)(lm_c & 0x7fffffffu);
        float c = m * f_c;
        lsum = fmaf(c, f_c, lsum);
        int a = la * 17 + l16;
        int l0 = __shfl(la, 0), l1 = __shfl(la, 16),
            l2 = __shfl(la, 32), l3 = __shfl(la, 48);
        bool dup = (l0 == l1) | (l0 == l2) | (l0 == l3) |
                   (l1 == l2) | (l1 == l3) | (l2 == l3);
        if (!dup) slice[a] += c;
        else      atomicAdd(&slice[a], c);
    }
    __syncthreads();

    float* myp = updp + (size_t)blockIdx.x * (NC * DD);
    for (int i = tid; i < NC * DD; i += 512) {
        int r = i >> 6, d = i & 63;
        int q = d >> 4, d16 = d & 15;
        myp[i] = sl[q * SLICE_F + r * 17 + d16] +
                 sl[(q + 4) * SLICE_F + r * 17 + d16];
    }
#pragma unroll
    for (int off = 32; off; off >>= 1) lsum += __shfl_xor(lsum, off);
    if (lane == 0) lred[w] = lsum;
    __syncthreads();
    if (tid == 0) {
        float s = 0.f;
#pragma unroll
        for (int ww = 0; ww < 8; ++ww) s += lred[ww];
        lossp[blockIdx.x] = s;
    }
}

// ---------------------------------------------------------------------------
// Kernel 4: grid NC*4+1. Block (j,q) reduces F over nb partials for 16 dims,
// writes new centers + loss piece partial. Last block reduces Sfeat.
// ---------------------------------------------------------------------------
__global__ __launch_bounds__(256) void k_reduce(const float* __restrict__ updp,
                                                const float* __restrict__ lossp,
                                                const float* __restrict__ centers,
                                                const int* __restrict__ counts,
                                                float* __restrict__ out,
                                                float* __restrict__ lossc, int nb) {
    __shared__ float sred[256];
    __shared__ float sr[4];
    int tid = threadIdx.x;
    int bid = blockIdx.x;
    if (bid < NC * 4) {
        int j = bid >> 2, q = bid & 3;
        int i = tid & 15;
        int c16 = tid >> 4;
        int per = nb >> 4;
        int col = j * DD + q * 16 + i;
        float s = 0.f;
        for (int b = c16 * per; b < (c16 + 1) * per; ++b)
            s += updp[(size_t)b * (NC * DD) + col];
        sred[tid] = s;
        __syncthreads();
        if (tid < 16) {
            float F = 0.f;
#pragma unroll
            for (int cc = 0; cc < 16; ++cc) F += sred[cc * 16 + i];
            float c   = centers[col];
            float cnt = (float)counts[j];
            float scale = ALPHA / (1.f + cnt);
            out[1 + col] = c - scale * (cnt * c - F);
            float lp = cnt * c * c - 2.f * c * F;
#pragma unroll
            for (int off = 8; off; off >>= 1) lp += __shfl_xor(lp, off);
            if (i == 0) lossc[bid] = lp;
        }
    } else {
        float s = 0.f;
        for (int t = tid; t < nb; t += 256) s += lossp[t];
#pragma unroll
        for (int off = 32; off; off >>= 1) s += __shfl_xor(s, off);
        int lane = tid & 63, wv = tid >> 6;
        if (lane == 0) sr[wv] = s;
        __syncthreads();
        if (tid == 0) lossc[NC * 4] = sr[0] + sr[1] + sr[2] + sr[3];
    }
}

// ---------------------------------------------------------------------------
// Kernel 5: out[0] = 0.5 * sum(lossc[0 .. NC*4])
// ---------------------------------------------------------------------------
__global__ __launch_bounds__(512) void k_final(const float* __restrict__ lossc,
                                               float* __restrict__ out) {
    __shared__ float sr[8];
    int tid = threadIdx.x;
    float s = (tid < NC * 4 + 1) ? lossc[tid] : 0.f;
#pragma unroll
    for (int off = 32; off; off >>= 1) s += __shfl_xor(s, off);
    int lane = tid & 63, wv = tid >> 6;
    if (lane == 0) sr[wv] = s;
    __syncthreads();
    if (tid == 0) {
        float t = 0.f;
#pragma unroll
        for (int w2 = 0; w2 < 8; ++w2) t += sr[w2];
        out[0] = 0.5f * t;
    }
}

// ---------------------------------------------------------------------------
extern "C" void kernel_launch(void* const* d_in, const int* in_sizes, int n_in,
                              void* d_out, int out_size, void* d_ws, size_t ws_size,
                              hipStream_t stream) {
    const float* preds    = (const float*)d_in[0];
    const float* features = (const float*)d_in[1];
    const int*   labels   = (const int*)d_in[2];
    const float* centers  = (const float*)d_in[3];
    float* out = (float*)d_out;

    char* ws = (char*)d_ws;
    unsigned char* pl  = (unsigned char*)ws;                    // BT bytes
    unsigned* labm     = (unsigned*)(ws + BT);                  // BT words
    int* counts        = (int*)(ws + 5 * (size_t)BT);           // 85 ints
    size_t off0 = 5 * (size_t)BT + 512;

    int nb = 768;
    while (nb > 16 && off0 + (size_t)nb * 4 + 1536 +
                      (size_t)nb * NC * DD * 4 > ws_size)
        nb >>= 1;
    float* lossp = (float*)(ws + off0);                         // nb floats
    float* lossc = (float*)(ws + off0 + (size_t)nb * 4);        // 341 floats
    float* updp  = (float*)(ws + off0 + (size_t)nb * 4 + 1536);

    hipMemsetAsync(counts, 0, NC * sizeof(int), stream);
    k_argmax<<<BT / 256, 256, 0, stream>>>((const float4*)preds, pl);
    k_mask<<<BT / 256, 256, 0, stream>>>(pl, labels, labm, counts);
    k_main<<<nb, 512, 0, stream>>>(features, labm, updp, lossp, nb);
    k_reduce<<<NC * 4 + 1, 256, 0, stream>>>(updp, lossp, centers, counts,
                                             out, lossc, nb);
    k_final<<<1, 512, 0, stream>>>(lossc, out);
}

// Round 5
// 123.274 us; speedup vs baseline: 2.1970x; 1.0966x over previous
//
#include <hip/hip_runtime.h>
#include <cstdint>

#define BB     4096
#define TT     96
#define NC     85
#define BLANKC 84
#define DD     64
#define ALPHA  0.05f
#define BT     (BB * TT)      // 393216
#define SLICE_F (NC * 17)     // 1445 floats per wave-private slice (pad 16->17)
#define RPB    128            // argmax rows per block
#define RSTR   92             // padded LDS row stride (92%32=28 -> 2-way scan, free)

// ---------------------------------------------------------------------------
// Kernel 1: argmax over 85 classes. 512 thr stage 128 rows (2720 contiguous
// float4s, fully coalesced) into a stride-92 LDS tile; then thread (r,q)
// register-scans column-quarter q of row r (f4 reads, 4-wide ILP); LDS combine
// across quarters with lowest-col tie-break. Block 0 also zeroes counts
// (stream order puts it before k_mask's atomics). 3072 blocks, 24 waves/CU.
// ---------------------------------------------------------------------------
__global__ __launch_bounds__(512) void k_argmax(const float4* __restrict__ p4,
                                                unsigned char* __restrict__ pl,
                                                int* __restrict__ counts) {
    __shared__ float rows[RPB * RSTR];             // 47104 B
    __shared__ float sv[512];
    __shared__ int   sc[512];
    int tid = threadIdx.x;
    if (blockIdx.x == 0 && tid < NC) counts[tid] = 0;

    // stage: 2720 coalesced float4 loads, scalar-scattered into padded rows
    const float4* src = p4 + (size_t)blockIdx.x * (RPB * NC / 4);
    for (int i = tid; i < RPB * NC / 4; i += 512) {
        float4 v = src[i];
        float vv[4] = {v.x, v.y, v.z, v.w};
        int e = i * 4;
#pragma unroll
        for (int j = 0; j < 4; ++j) {
            int ee = e + j;                        // 0 .. 10879
            int r = ee / NC;                       // magic-mul
            int c = ee - r * NC;
            rows[r * RSTR + c] = vv[j];
        }
    }
    // pad cols 85..87 = -inf (only f4 indices 0..21 are ever read)
    for (int s = tid; s < RPB * 3; s += 512)
        rows[(s / 3) * RSTR + NC + s % 3] = -3.4e38f;
    __syncthreads();

    // scan: thread = q*128 + r ; q wave-uniform (q = wave>>1)
    int r = tid & (RPB - 1);
    int q = tid >> 7;
    const int f0i[4] = {0, 6, 12, 17};
    const int f1i[4] = {6, 12, 17, 22};
    const float* my = &rows[r * RSTR];
    float bv = -3.4e38f; int bc = 127;
    for (int i = f0i[q]; i < f1i[q]; ++i) {
        float4 v = *(const float4*)(my + i * 4);   // 16B aligned: RSTR%4==0
        float vv[4] = {v.x, v.y, v.z, v.w};
#pragma unroll
        for (int j = 0; j < 4; ++j) {
            int c = i * 4 + j;
            if (vv[j] > bv) { bv = vv[j]; bc = c; }
        }
    }
    sv[tid] = bv; sc[tid] = bc;
    __syncthreads();

    if (tid < RPB) {
        float v0 = sv[tid]; int c0 = sc[tid];
#pragma unroll
        for (int qq = 1; qq < 4; ++qq) {
            float v = sv[qq * RPB + tid];
            int   c = sc[qq * RPB + tid];
            if (v > v0) { v0 = v; c0 = c; }        // strict >: lower q (col) wins ties
        }
        pl[blockIdx.x * RPB + tid] = (unsigned char)c0;
    }
}

// ---------------------------------------------------------------------------
// Kernel 2: CTC mask + per-class counts + packed label/mask word.
// labm[idx] = label | (mask << 31)
// ---------------------------------------------------------------------------
__global__ __launch_bounds__(256) void k_mask(const unsigned char* __restrict__ pl,
                                              const int* __restrict__ labels,
                                              unsigned* __restrict__ labm,
                                              int* __restrict__ counts) {
    __shared__ int h[NC];
    int tid = threadIdx.x;
    if (tid < NC) h[tid] = 0;
    __syncthreads();
    int idx = blockIdx.x * 256 + tid;
    int p = pl[idx];
    int t = idx % TT;
    unsigned m = (p != BLANKC) && (t == TT - 1 || p != pl[idx + 1]);
    labm[idx] = (unsigned)labels[idx] | (m << 31);
    atomicAdd(&h[labels[idx]], (int)m);
    __syncthreads();
    if (tid < NC && h[tid]) atomicAdd(&counts[tid], h[tid]);
}

// ---------------------------------------------------------------------------
// Kernel 3: masked feature segment-sum, NO LDS atomics on the hot path.
// 8 waves/block; wave w owns dim-quad dq=w&3 with a PRIVATE slice [85][17].
// Per step a wave handles 4 positions x 16 dims; plain ds_read+fma+ds_write
// when the 4 labels are distinct (93%); atomic fallback otherwise.
// ---------------------------------------------------------------------------
__global__ __launch_bounds__(512) void k_main(const float* __restrict__ feat,
                                              const unsigned* __restrict__ labm,
                                              float* __restrict__ updp,
                                              float* __restrict__ lossp, int nb) {
    __shared__ float sl[8 * SLICE_F];              // 46240 B
    __shared__ float lred[8];
    int tid = threadIdx.x;
    for (int i = tid; i < 8 * SLICE_F; i += 512) sl[i] = 0.f;
    __syncthreads();

    int lane = tid & 63;
    int w    = tid >> 6;
    int dq   = w & 3;
    int wg   = w >> 2;
    int sub  = lane >> 4;
    int l16  = lane & 15;
    float* slice = sl + w * SLICE_F;

    int ppc    = BT / (nb * 2);
    int p0     = (blockIdx.x * 2 + wg) * ppc;
    int nsteps = ppc / 4;

    float lsum = 0.f;
    unsigned lm = labm[p0 + sub];
    float    f  = feat[(size_t)(p0 + sub) * DD + dq * 16 + l16];

    for (int s = 0; s < nsteps; ++s) {
        unsigned lm_c = lm; float f_c = f;
        if (s + 1 < nsteps) {
            int pn = p0 + (s + 1) * 4 + sub;
            lm = labm[pn];
            f  = feat[(size_t)pn * DD + dq * 16 + l16];
        }
        float m = (float)(lm_c >> 31);
        int  la = (int)(lm_c & 0x7fffffffu);
        float c = m * f_c;
        lsum = fmaf(c, f_c, lsum);
        int a = la * 17 + l16;
        int l0 = __shfl(la, 0), l1 = __shfl(la, 16),
            l2 = __shfl(la, 32), l3 = __shfl(la, 48);
        bool dup = (l0 == l1) | (l0 == l2) | (l0 == l3) |
                   (l1 == l2) | (l1 == l3) | (l2 == l3);
        if (!dup) slice[a] += c;
        else      atomicAdd(&slice[a], c);
    }
    __syncthreads();

    float* myp = updp + (size_t)blockIdx.x * (NC * DD);
    for (int i = tid; i < NC * DD; i += 512) {
        int r = i >> 6, d = i & 63;
        int q = d >> 4, d16 = d & 15;
        myp[i] = sl[q * SLICE_F + r * 17 + d16] +
                 sl[(q + 4) * SLICE_F + r * 17 + d16];
    }
#pragma unroll
    for (int off = 32; off; off >>= 1) lsum += __shfl_xor(lsum, off);
    if (lane == 0) lred[w] = lsum;
    __syncthreads();
    if (tid == 0) {
        float s = 0.f;
#pragma unroll
        for (int ww = 0; ww < 8; ++ww) s += lred[ww];
        lossp[blockIdx.x] = s;
    }
}

// ---------------------------------------------------------------------------
// Kernel 4: grid NC*4+1. Block (j,q) reduces F over nb partials for 16 dims,
// writes new centers + loss piece partial. Last block reduces Sfeat.
// ---------------------------------------------------------------------------
__global__ __launch_bounds__(256) void k_reduce(const float* __restrict__ updp,
                                                const float* __restrict__ lossp,
                                                const float* __restrict__ centers,
                                                const int* __restrict__ counts,
                                                float* __restrict__ out,
                                                float* __restrict__ lossc, int nb) {
    __shared__ float sred[256];
    __shared__ float sr[4];
    int tid = threadIdx.x;
    int bid = blockIdx.x;
    if (bid < NC * 4) {
        int j = bid >> 2, q = bid & 3;
        int i = tid & 15;
        int c16 = tid >> 4;
        int per = nb >> 4;
        int col = j * DD + q * 16 + i;
        float s = 0.f;
        for (int b = c16 * per; b < (c16 + 1) * per; ++b)
            s += updp[(size_t)b * (NC * DD) + col];
        sred[tid] = s;
        __syncthreads();
        if (tid < 16) {
            float F = 0.f;
#pragma unroll
            for (int cc = 0; cc < 16; ++cc) F += sred[cc * 16 + i];
            float c   = centers[col];
            float cnt = (float)counts[j];
            float scale = ALPHA / (1.f + cnt);
            out[1 + col] = c - scale * (cnt * c - F);
            float lp = cnt * c * c - 2.f * c * F;
#pragma unroll
            for (int off = 8; off; off >>= 1) lp += __shfl_xor(lp, off);
            if (i == 0) lossc[bid] = lp;
        }
    } else {
        float s = 0.f;
        for (int t = tid; t < nb; t += 256) s += lossp[t];
#pragma unroll
        for (int off = 32; off; off >>= 1) s += __shfl_xor(s, off);
        int lane = tid & 63, wv = tid >> 6;
        if (lane == 0) sr[wv] = s;
        __syncthreads();
        if (tid == 0) lossc[NC * 4] = sr[0] + sr[1] + sr[2] + sr[3];
    }
}

// ---------------------------------------------------------------------------
// Kernel 5: out[0] = 0.5 * sum(lossc[0 .. NC*4])
// ---------------------------------------------------------------------------
__global__ __launch_bounds__(512) void k_final(const float* __restrict__ lossc,
                                               float* __restrict__ out) {
    __shared__ float sr[8];
    int tid = threadIdx.x;
    float s = (tid < NC * 4 + 1) ? lossc[tid] : 0.f;
#pragma unroll
    for (int off = 32; off; off >>= 1) s += __shfl_xor(s, off);
    int lane = tid & 63, wv = tid >> 6;
    if (lane == 0) sr[wv] = s;
    __syncthreads();
    if (tid == 0) {
        float t = 0.f;
#pragma unroll
        for (int w2 = 0; w2 < 8; ++w2) t += sr[w2];
        out[0] = 0.5f * t;
    }
}

// ---------------------------------------------------------------------------
extern "C" void kernel_launch(void* const* d_in, const int* in_sizes, int n_in,
                              void* d_out, int out_size, void* d_ws, size_t ws_size,
                              hipStream_t stream) {
    const float* preds    = (const float*)d_in[0];
    const float* features = (const float*)d_in[1];
    const int*   labels   = (const int*)d_in[2];
    const float* centers  = (const float*)d_in[3];
    float* out = (float*)d_out;

    char* ws = (char*)d_ws;
    unsigned char* pl  = (unsigned char*)ws;                    // BT bytes
    unsigned* labm     = (unsigned*)(ws + BT);                  // BT words
    int* counts        = (int*)(ws + 5 * (size_t)BT);           // 85 ints
    size_t off0 = 5 * (size_t)BT + 512;

    int nb = 768;
    while (nb > 16 && off0 + (size_t)nb * 4 + 1536 +
                      (size_t)nb * NC * DD * 4 > ws_size)
        nb >>= 1;
    float* lossp = (float*)(ws + off0);                         // nb floats
    float* lossc = (float*)(ws + off0 + (size_t)nb * 4);        // 341 floats
    float* updp  = (float*)(ws + off0 + (size_t)nb * 4 + 1536);

    k_argmax<<<BT / RPB, 512, 0, stream>>>((const float4*)preds, pl, counts);
    k_mask<<<BT / 256, 256, 0, stream>>>(pl, labels, labm, counts);
    k_main<<<nb, 512, 0, stream>>>(features, labm, updp, lossp, nb);
    k_reduce<<<NC * 4 + 1, 256, 0, stream>>>(updp, lossp, centers, counts,
                                             out, lossc, nb);
    k_final<<<1, 512, 0, stream>>>(lossc, out);
}